// Round 16
// baseline (11157.986 us; speedup 1.0000x reference)
//
#include <hip/hip_runtime.h>
#include <hip/hip_fp16.h>

typedef unsigned short ushort_t;
typedef unsigned int uint_t;

#define BN 512
#define LN 1024
#define FN 38
#define HN 256
#define ZDN 4
#define FXN 64
#define FZN 32

#define NT 512
#define NWG 32
#define BT 16

// weight-fragment entry bases (entry = 64 lanes x 16 B = 1 KB)
#define RB 0      // r gate:  16 mt x 11 ks
#define ZB 176    // z gate:  16 mt x 11 ks
#define HB 352    // hn gate: 16 mt x 8 ks (h only)
#define IB 480    // in gate: 16 mt x 3 ks (x only)
#define TB 528    // theta:   3 mt x 9 ks ([fz|h])
#define PB 555    // phi:     1 mt x 10 ks ([h|fx])
#define NENT 565

__device__ __forceinline__ ushort_t f2h(float f) { return __half_as_ushort(__float2half(f)); }
__device__ __forceinline__ float h2f(ushort_t u) { return __half2float(__ushort_as_half(u)); }
__device__ __forceinline__ uint_t pk2(float a, float b) {
    return (uint_t)f2h(a) | ((uint_t)f2h(b) << 16);
}
// fast transcendentals (v_exp_f32 / v_log_f32 based)
__device__ __forceinline__ float fsig(float v) { return 1.0f / (1.0f + __expf(-v)); }
__device__ __forceinline__ float ftanh(float v) { return 1.0f - 2.0f / (__expf(2.0f * v) + 1.0f); }
__device__ __forceinline__ float fsoftplus(float v) {
    return fmaxf(v, 0.0f) + __logf(1.0f + __expf(-fabsf(v)));
}

typedef _Float16 h8 __attribute__((ext_vector_type(8)));
typedef float f4 __attribute__((ext_vector_type(4)));
#define MFMA(A, B, C) __builtin_amdgcn_mfma_f32_16x16x32_f16((A), (B), (C), 0, 0, 0)
__device__ __forceinline__ h8 bch8(uint4 v) { return __builtin_bit_cast(h8, v); }

// A-frag layout per entry: lane ln holds row = ln&15, k = (ln>>4)*8 + i (i=0..7).
// act k-space: 0..255 h (W_hh cols), 256..319 fx (W_ih 0..63), 320..351 fz (W_ih 64..95)
__global__ __launch_bounds__(256) void repack_frags(
    const float* __restrict__ W_ih, const float* __restrict__ W_hh,
    const float* __restrict__ Wt_loc,
    const float* __restrict__ Wp_loc, const float* __restrict__ Wp_scale,
    ushort_t* __restrict__ wfrag) {
    int idx = blockIdx.x * 256 + threadIdx.x;        // over NENT*512 f16
    if (idx >= NENT * 512) return;
    int e = idx >> 9, r512 = idx & 511, ln = r512 >> 3, i = r512 & 7;
    int row = ln & 15, kl = ((ln >> 4) << 3) + i;    // kl in 0..31
    float v = 0.0f;
    if (e < ZB) {                       // r
        int mt = e / 11, ks = e % 11, j = mt * 16 + row, ak = ks * 32 + kl;
        v = (ak < 256) ? W_hh[j * 256 + ak] : W_ih[j * 96 + ak - 256];
    } else if (e < HB) {                // z
        int e2 = e - ZB, mt = e2 / 11, ks = e2 % 11, j = mt * 16 + row, ak = ks * 32 + kl;
        v = (ak < 256) ? W_hh[(256 + j) * 256 + ak] : W_ih[(256 + j) * 96 + ak - 256];
    } else if (e < IB) {                // hn (h part)
        int e2 = e - HB, mt = e2 / 8, ks = e2 % 8, j = mt * 16 + row;
        v = W_hh[(512 + j) * 256 + ks * 32 + kl];
    } else if (e < TB) {                // in (x part)
        int e2 = e - IB, mt = e2 / 3, ksx = e2 % 3, j = mt * 16 + row;
        v = W_ih[(512 + j) * 96 + ksx * 32 + kl];
    } else if (e < PB) {                // theta, k-order [fz | h]
        int e2 = e - TB, mtt = e2 / 9, tks = e2 % 9, f = mtt * 16 + row;
        int col = (tks == 0) ? kl : 32 + (tks - 1) * 32 + kl;
        v = (f < FN) ? Wt_loc[f * 288 + col] : 0.0f;
    } else {                            // phi: rows 0-3 loc, 4-7 scale, k [h|fx]
        int ks = e - PB, col = ks * 32 + kl;
        if (row < 4) v = Wp_loc[row * 320 + col];
        else if (row < 8) v = Wp_scale[(row - 4) * 320 + col];
    }
    wfrag[idx] = f2h(v);
}

// fx = relu(x @ Wx^T + bx) for all (b,l), stored f16-packed [B][L][64].
__global__ __launch_bounds__(256) void fx_pre(const float* __restrict__ x,
                                              const float* __restrict__ Wx,
                                              const float* __restrict__ bx,
                                              ushort_t* __restrict__ fxbuf) {
    __shared__ float w[FXN][FN + 1];
    __shared__ float bxs[FXN];
    int t = threadIdx.x;
    for (int i = t; i < FXN * FN; i += 256) w[i / FN][i % FN] = Wx[i];
    if (t < FXN) bxs[t] = bx[t];
    __syncthreads();
    size_t id = (size_t)blockIdx.x * 256 + t;
    const float* xr = x + id * FN;
    float xv[FN];
#pragma unroll
    for (int f = 0; f < FN; ++f) xv[f] = xr[f];
    uint4* dst = (uint4*)(fxbuf + id * FXN);
#pragma unroll
    for (int e8 = 0; e8 < 8; ++e8) {
        float a[8];
#pragma unroll
        for (int u = 0; u < 8; ++u) {
            int e = e8 * 8 + u;
            float acc = bxs[e];
#pragma unroll
            for (int f = 0; f < FN; ++f) acc += xv[f] * w[e][f];
            a[u] = fmaxf(acc, 0.0f);
        }
        uint4 o;
        o.x = pk2(a[0], a[1]); o.y = pk2(a[2], a[3]);
        o.z = pk2(a[4], a[5]); o.w = pk2(a[6], a[7]);
        dst[e8] = o;
    }
}

// act-frag index: buffer buf, k-step ks -> base in ushorts (single n-tile)
#define AIDX(buf, ks) (((buf) * 11 + (ks)) * 512)

template <bool FXPRE>
__global__ __launch_bounds__(NT) void vrnn_mfma(
    const float* __restrict__ x, const float* __restrict__ eps,
    const float* __restrict__ Wx, const float* __restrict__ bx,
    const float* __restrict__ Wz1, const float* __restrict__ bz1,
    const float* __restrict__ Wz2, const float* __restrict__ bz2,
    const float* __restrict__ bp_loc, const float* __restrict__ bp_scale,
    const float* __restrict__ bt_loc,
    const float* __restrict__ b_ih, const float* __restrict__ b_hh,
    const ushort_t* __restrict__ wfrag, const ushort_t* __restrict__ fxbuf,
    float* __restrict__ out)
{
    __shared__ __attribute__((aligned(16))) ushort_t actf[2 * 11 * 512];     // 22.5 KB frags
    __shared__ __attribute__((aligned(16))) uint_t phif[10 * 64 * 4];        // phi A-frags
    __shared__ __attribute__((aligned(16))) ushort_t wext[75 * 512];         // in(48)+theta(27)
    __shared__ float pp[8][16];
    __shared__ float bsr[HN], bsz[HN], bin_[HN], bhn_[HN];
    __shared__ float wz1s[16][ZDN], wz2s[FZN][16];
    __shared__ float bz1s[16], bz2s[FZN], btls[FN], bpls[ZDN], bpss[ZDN];
    __shared__ float wxs[FXN][FN + 2], bxs[FXN];     // tier-B fx weights

    const int t = threadIdx.x;
    const int w = t >> 6, ln = t & 63;
    const int b0 = blockIdx.x * BT;
    const uint4* WL = ((const uint4*)wfrag) + ln;    // lane-offset entry table

    // ---- one-time init
    {
        const uint_t* wfu = (const uint_t*)wfrag;
        for (int i = t; i < 10 * 256; i += NT) phif[i] = wfu[PB * 256 + i];
        uint2* we2 = (uint2*)wext;
        const uint2* ws2 = ((const uint2*)wfrag) + IB * 128;
        for (int i = t; i < 75 * 128; i += NT) we2[i] = ws2[i];
    }
    if (t < HN) {
        bsr[t] = b_ih[t] + b_hh[t];
        bsz[t] = b_ih[HN + t] + b_hh[HN + t];
        bin_[t] = b_ih[2 * HN + t];
        bhn_[t] = b_hh[2 * HN + t];
    }
    if (t >= 256 && t < 320) ((float*)wz1s)[t - 256] = Wz1[t - 256];
    for (int i = t; i < FZN * 16; i += NT) ((float*)wz2s)[i] = Wz2[i];
    if (t < 16) bz1s[t] = bz1[t];
    if (t >= 32 && t < 64) bz2s[t - 32] = bz2[t - 32];
    if (t >= 64 && t < 64 + FN) btls[t - 64] = bt_loc[t - 64];
    if (t >= 128 && t < 132) bpls[t - 128] = bp_loc[t - 128];
    if (t >= 160 && t < 164) bpss[t - 160] = bp_scale[t - 160];
    if (!FXPRE) {
        for (int i = t; i < FXN * FN; i += NT) wxs[i / FN][i % FN] = Wx[i];
        if (t >= 320 && t < 384) bxs[t - 320] = bx[t - 320];
    }
    // zero h-region of buffer 0 (ksteps 0..7)
    for (int i = t; i < 8 * 512; i += NT) actf[AIDX(0, i >> 9) + (i & 511)] = 0;
    __syncthreads();
    // fx(l=0) into buffer 0 (threads 0..127: b 0..15, ch 0..7)
    if (t < 128) {
        int b = t >> 3, ch = t & 7;
        int dst = AIDX(0, 8 + (ch >> 2)) + ((ch & 3) * 16 + b) * 8;
        if (FXPRE) {
            uint4 v = ((const uint4*)fxbuf)[((size_t)(b0 + b) * LN) * 8 + ch];
            *(uint4*)&actf[dst] = v;
        } else {
            const float* xr = x + ((size_t)(b0 + b) * LN) * FN;
            uint_t o[4];
#pragma unroll
            for (int p = 0; p < 4; ++p) {
                float a0 = bxs[ch * 8 + 2 * p], a1 = bxs[ch * 8 + 2 * p + 1];
#pragma unroll
                for (int f = 0; f < FN; ++f) {
                    float xv = xr[f];
                    a0 += xv * wxs[ch * 8 + 2 * p][f];
                    a1 += xv * wxs[ch * 8 + 2 * p + 1][f];
                }
                o[p] = pk2(fmaxf(a0, 0.0f), fmaxf(a1, 0.0f));
            }
            *(uint4*)&actf[dst] = make_uint4(o[0], o[1], o[2], o[3]);
        }
    }
    __syncthreads();

    const int mtA = 2 * w, mtB = 2 * w + 1;

    // persistent h registers (each thread owns the same 8 h-values all steps)
    float hA[4] = {0, 0, 0, 0}, hB[4] = {0, 0, 0, 0};

#pragma unroll 1
    for (int l = 0; l < LN; ++l) {
        const int cur = l & 1, nxt = cur ^ 1;

        // eps prefetch for CDE threads (waves 4-5)
        float4 pfe = {0, 0, 0, 0};
        if (t >= 256 && t < 384)
            pfe = *(const float4*)&eps[((size_t)l * BN + b0 + ((t - 256) >> 3)) * ZDN];

        // ---- fused MFMA loop, depth-2 rotation on r/z/hn A-frags
        f4 ra0 = {0,0,0,0}, rb0 = {0,0,0,0}, za0 = {0,0,0,0}, zb0 = {0,0,0,0};
        f4 na0 = {0,0,0,0}, nb0 = {0,0,0,0}, ia0 = {0,0,0,0}, ib0 = {0,0,0,0};
        f4 tp = {0,0,0,0};

        uint4 rac = WL[(RB + mtA * 11 + 0) * 64], rbc = WL[(RB + mtB * 11 + 0) * 64];
        uint4 zac = WL[(ZB + mtA * 11 + 0) * 64], zbc = WL[(ZB + mtB * 11 + 0) * 64];
        uint4 ran = WL[(RB + mtA * 11 + 1) * 64], rbn = WL[(RB + mtB * 11 + 1) * 64];
        uint4 zan = WL[(ZB + mtA * 11 + 1) * 64], zbn = WL[(ZB + mtB * 11 + 1) * 64];
        uint4 hac = WL[(HB + mtA * 8 + 0) * 64],  hbc = WL[(HB + mtB * 8 + 0) * 64];
        uint4 han = WL[(HB + mtA * 8 + 1) * 64],  hbn = WL[(HB + mtB * 8 + 1) * 64];

#pragma unroll
        for (int ks = 0; ks < 10; ++ks) {
            h8 B = *(const h8*)&actf[AIDX(cur, ks) + ln * 8];
            ra0 = MFMA(bch8(rac), B, ra0);
            rac = ran; if (ks < 9) ran = WL[(RB + mtA * 11 + ks + 2) * 64];
            rb0 = MFMA(bch8(rbc), B, rb0);
            rbc = rbn; if (ks < 9) rbn = WL[(RB + mtB * 11 + ks + 2) * 64];
            za0 = MFMA(bch8(zac), B, za0);
            zac = zan; if (ks < 9) zan = WL[(ZB + mtA * 11 + ks + 2) * 64];
            zb0 = MFMA(bch8(zbc), B, zb0);
            zbc = zbn; if (ks < 9) zbn = WL[(ZB + mtB * 11 + ks + 2) * 64];
            if (ks < 8) {
                na0 = MFMA(bch8(hac), B, na0);
                hac = han; if (ks < 6) han = WL[(HB + mtA * 8 + ks + 2) * 64];
                nb0 = MFMA(bch8(hbc), B, nb0);
                hbc = hbn; if (ks < 6) hbn = WL[(HB + mtB * 8 + ks + 2) * 64];
            } else {
                h8 wA = *(const h8*)&wext[(mtA * 3 + (ks - 8)) * 512 + ln * 8];
                h8 wB = *(const h8*)&wext[(mtB * 3 + (ks - 8)) * 512 + ln * 8];
                ia0 = MFMA(wA, B, ia0);
                ib0 = MFMA(wB, B, ib0);
            }
            if (w < 3) {
                if (ks < 8) {
                    h8 wt = *(const h8*)&wext[(48 + w * 9 + ks + 1) * 512 + ln * 8];
                    tp = MFMA(wt, B, tp);
                }
            } else if (w == 3) {
                uint4 pa = *(const uint4*)&phif[(ks * 64 + ln) * 4];
                tp = MFMA(bch8(pa), B, tp);
            }
        }
        if (w == 3 && (ln >> 4) < 2) {            // dump phi D -> pp
#pragma unroll
            for (int q = 0; q < 4; ++q) pp[(ln >> 4) * 4 + q][ln & 15] = tp[q];
        }
        __syncthreads();   // sync1: pp ready

        // ---- CDE (waves 4-5): z -> f1 -> fz; fx(l+1) staging (waves 6-7)
        if (t >= 256 && t < 384) {
            int tid = t - 256, b = tid >> 3, part = tid & 7;
            float ez[4] = {pfe.x, pfe.y, pfe.z, pfe.w};
            float zz[4];
#pragma unroll
            for (int c = 0; c < 4; ++c)
                zz[c] = pp[c][b] + bpls[c] + fsoftplus(pp[4 + c][b] + bpss[c]) * ez[c];
            float f1v[16];
#pragma unroll
            for (int k = 0; k < 16; ++k) {
                float a = bz1s[k];
#pragma unroll
                for (int c = 0; c < 4; ++c) a += zz[c] * wz1s[k][c];
                f1v[k] = fmaxf(a, 0.0f);
            }
            float v4[4];
#pragma unroll
            for (int oq = 0; oq < 4; ++oq) {
                int o = part * 4 + oq;
                float acc = bz2s[o];
#pragma unroll
                for (int k = 0; k < 16; ++k) acc += f1v[k] * wz2s[o][k];
                v4[oq] = fmaxf(acc, 0.0f);
            }
            uint2 pk; pk.x = pk2(v4[0], v4[1]); pk.y = pk2(v4[2], v4[3]);
            int dst = AIDX(cur, 10) + ((part >> 1) * 16 + b) * 8 + (part & 1) * 4;
            *(uint2*)&actf[dst] = pk;
        } else if (t >= 384) {
            int tid = t - 384, b = tid >> 3, ch = tid & 7;
            int lp = (l + 1 < LN) ? l + 1 : LN - 1;
            int dst = AIDX(nxt, 8 + (ch >> 2)) + ((ch & 3) * 16 + b) * 8;
            if (FXPRE) {
                uint4 v = ((const uint4*)fxbuf)[((size_t)(b0 + b) * LN + lp) * 8 + ch];
                *(uint4*)&actf[dst] = v;
            } else {
                const float* xr = x + ((size_t)(b0 + b) * LN + lp) * FN;
                uint_t o[4];
#pragma unroll
                for (int p = 0; p < 4; ++p) {
                    float a0 = bxs[ch * 8 + 2 * p], a1 = bxs[ch * 8 + 2 * p + 1];
#pragma unroll
                    for (int f = 0; f < FN; ++f) {
                        float xv = xr[f];
                        a0 += xv * wxs[ch * 8 + 2 * p][f];
                        a1 += xv * wxs[ch * 8 + 2 * p + 1][f];
                    }
                    o[p] = pk2(fmaxf(a0, 0.0f), fmaxf(a1, 0.0f));
                }
                *(uint4*)&actf[dst] = make_uint4(o[0], o[1], o[2], o[3]);
            }
        }
        __syncthreads();   // sync2: fz ready

        // ---- Phase B: fz kstep (rotated r/z regs hold ks10; in/theta from LDS)
        {
            h8 B = *(const h8*)&actf[AIDX(cur, 10) + ln * 8];
            ra0 = MFMA(bch8(rac), B, ra0);
            rb0 = MFMA(bch8(rbc), B, rb0);
            za0 = MFMA(bch8(zac), B, za0);
            zb0 = MFMA(bch8(zbc), B, zb0);
            h8 wA = *(const h8*)&wext[(mtA * 3 + 2) * 512 + ln * 8];
            h8 wB = *(const h8*)&wext[(mtB * 3 + 2) * 512 + ln * 8];
            ia0 = MFMA(wA, B, ia0);
            ib0 = MFMA(wB, B, ib0);
            if (w < 3) {
                h8 wt = *(const h8*)&wext[(48 + w * 9 + 0) * 512 + ln * 8];
                tp = MFMA(wt, B, tp);
            }
        }

        if (w < 3) {    // theta store early: vmcnt drain overlaps PW VALU
            int bb = b0 + (ln & 15);
            float* op = out + ((size_t)bb * LN + l) * FN;
#pragma unroll
            for (int q = 0; q < 4; ++q) {
                int f = w * 16 + ((ln >> 4) << 2) + q;
                if (f < FN) op[f] = tp[q] + btls[f];
            }
        }

#define PW(RACC, ZACC, NACC, IACC, MTL, HARR) do {                                  \
        int jb = (2 * w + (MTL)) * 16 + ((ln >> 4) << 2);                           \
        int abase = (((jb >> 3) & 3) * 16 + (ln & 15)) * 8 + (jb & 7);              \
        float hn4[4];                                                               \
        _Pragma("unroll")                                                           \
        for (int q = 0; q < 4; ++q) {                                               \
            float r_ = fsig((RACC)[q] + bsr[jb + q]);                               \
            float z_ = fsig((ZACC)[q] + bsz[jb + q]);                               \
            float n_ = ftanh((IACC)[q] + bin_[jb + q] + r_ * ((NACC)[q] + bhn_[jb + q])); \
            hn4[q] = (1.0f - z_) * n_ + z_ * (HARR)[q];                             \
            (HARR)[q] = hn4[q];                                                     \
        }                                                                           \
        uint2 hw2; hw2.x = pk2(hn4[0], hn4[1]); hw2.y = pk2(hn4[2], hn4[3]);        \
        *(uint2*)&actf[AIDX(nxt, jb >> 5) + abase] = hw2;                           \
    } while (0)

        PW(ra0, za0, na0, ia0, 0, hA);
        PW(rb0, zb0, nb0, ib0, 1, hB);
#undef PW

        __syncthreads();   // sync3
    }
}

extern "C" void kernel_launch(void* const* d_in, const int* in_sizes, int n_in,
                              void* d_out, int out_size, void* d_ws, size_t ws_size,
                              hipStream_t stream) {
    const float* x        = (const float*)d_in[0];
    const float* eps      = (const float*)d_in[1];
    const float* Wx       = (const float*)d_in[2];
    const float* bx       = (const float*)d_in[3];
    const float* Wz1      = (const float*)d_in[4];
    const float* bz1      = (const float*)d_in[5];
    const float* Wz2      = (const float*)d_in[6];
    const float* bz2      = (const float*)d_in[7];
    const float* Wp_loc   = (const float*)d_in[8];
    const float* bp_loc   = (const float*)d_in[9];
    const float* Wp_scale = (const float*)d_in[10];
    const float* bp_scale = (const float*)d_in[11];
    const float* Wt_loc   = (const float*)d_in[12];
    const float* bt_loc   = (const float*)d_in[13];
    const float* W_ih     = (const float*)d_in[16];
    const float* W_hh     = (const float*)d_in[17];
    const float* b_ih     = (const float*)d_in[18];
    const float* b_hh     = (const float*)d_in[19];
    float* out = (float*)d_out;

    const size_t wfS = (size_t)NENT * 512;        // shorts
    const size_t fxS = (size_t)BN * LN * FXN;     // shorts

    ushort_t* wfrag = (ushort_t*)d_ws;
    ushort_t* fxbuf = wfrag + wfS;

    repack_frags<<<(int)((wfS + 255) / 256), 256, 0, stream>>>(
        W_ih, W_hh, Wt_loc, Wp_loc, Wp_scale, wfrag);

    if (ws_size >= (wfS + fxS) * sizeof(ushort_t)) {
        fx_pre<<<BN * LN / 256, 256, 0, stream>>>(x, Wx, bx, fxbuf);
        vrnn_mfma<true><<<NWG, NT, 0, stream>>>(
            x, eps, Wx, bx, Wz1, bz1, Wz2, bz2, bp_loc, bp_scale, bt_loc,
            b_ih, b_hh, wfrag, fxbuf, out);
    } else {
        vrnn_mfma<false><<<NWG, NT, 0, stream>>>(
            x, eps, Wx, bx, Wz1, bz1, Wz2, bz2, bp_loc, bp_scale, bt_loc,
            b_ih, b_hh, wfrag, (const ushort_t*)nullptr, out);
    }
}

// Round 17
// 9678.167 us; speedup vs baseline: 1.1529x; 1.1529x over previous
//
#include <hip/hip_runtime.h>
#include <hip/hip_fp16.h>

typedef unsigned short ushort_t;
typedef unsigned int uint_t;

#define BN 512
#define LN 1024
#define FN 38
#define HN 256
#define ZDN 4
#define FXN 64
#define FZN 32

#define NT 512
#define NWG 32
#define BT 16

// weight-fragment entry bases (entry = 64 lanes x 16 B = 1 KB)
#define RB 0      // r gate:  16 mt x 11 ks
#define ZB 176    // z gate:  16 mt x 11 ks
#define HB 352    // hn gate: 16 mt x 8 ks (h only)
#define IB 480    // in gate: 16 mt x 3 ks (x only)
#define TB 528    // theta:   3 mt x 9 ks ([fz|h])
#define PB 555    // phi:     1 mt x 10 ks ([h|fx])
#define NENT 565

__device__ __forceinline__ ushort_t f2h(float f) { return __half_as_ushort(__float2half(f)); }
__device__ __forceinline__ float h2f(ushort_t u) { return __half2float(__ushort_as_half(u)); }
__device__ __forceinline__ uint_t pk2(float a, float b) {
    return (uint_t)f2h(a) | ((uint_t)f2h(b) << 16);
}
// fast transcendentals (v_exp_f32 / v_log_f32 based)
__device__ __forceinline__ float fsig(float v) { return 1.0f / (1.0f + __expf(-v)); }
__device__ __forceinline__ float ftanh(float v) { return 1.0f - 2.0f / (__expf(2.0f * v) + 1.0f); }
__device__ __forceinline__ float fsoftplus(float v) {
    return fmaxf(v, 0.0f) + __logf(1.0f + __expf(-fabsf(v)));
}

typedef _Float16 h8 __attribute__((ext_vector_type(8)));
typedef float f4 __attribute__((ext_vector_type(4)));
#define MFMA(A, B, C) __builtin_amdgcn_mfma_f32_16x16x32_f16((A), (B), (C), 0, 0, 0)
__device__ __forceinline__ h8 bch8(uint4 v) { return __builtin_bit_cast(h8, v); }

// A-frag layout per entry: lane ln holds row = ln&15, k = (ln>>4)*8 + i (i=0..7).
// act k-space: 0..255 h (W_hh cols), 256..319 fx (W_ih 0..63), 320..351 fz (W_ih 64..95)
__global__ __launch_bounds__(256) void repack_frags(
    const float* __restrict__ W_ih, const float* __restrict__ W_hh,
    const float* __restrict__ Wt_loc,
    const float* __restrict__ Wp_loc, const float* __restrict__ Wp_scale,
    ushort_t* __restrict__ wfrag) {
    int idx = blockIdx.x * 256 + threadIdx.x;        // over NENT*512 f16
    if (idx >= NENT * 512) return;
    int e = idx >> 9, r512 = idx & 511, ln = r512 >> 3, i = r512 & 7;
    int row = ln & 15, kl = ((ln >> 4) << 3) + i;    // kl in 0..31
    float v = 0.0f;
    if (e < ZB) {                       // r
        int mt = e / 11, ks = e % 11, j = mt * 16 + row, ak = ks * 32 + kl;
        v = (ak < 256) ? W_hh[j * 256 + ak] : W_ih[j * 96 + ak - 256];
    } else if (e < HB) {                // z
        int e2 = e - ZB, mt = e2 / 11, ks = e2 % 11, j = mt * 16 + row, ak = ks * 32 + kl;
        v = (ak < 256) ? W_hh[(256 + j) * 256 + ak] : W_ih[(256 + j) * 96 + ak - 256];
    } else if (e < IB) {                // hn (h part)
        int e2 = e - HB, mt = e2 / 8, ks = e2 % 8, j = mt * 16 + row;
        v = W_hh[(512 + j) * 256 + ks * 32 + kl];
    } else if (e < TB) {                // in (x part)
        int e2 = e - IB, mt = e2 / 3, ksx = e2 % 3, j = mt * 16 + row;
        v = W_ih[(512 + j) * 96 + ksx * 32 + kl];
    } else if (e < PB) {                // theta, k-order [fz | h]
        int e2 = e - TB, mtt = e2 / 9, tks = e2 % 9, f = mtt * 16 + row;
        int col = (tks == 0) ? kl : 32 + (tks - 1) * 32 + kl;
        v = (f < FN) ? Wt_loc[f * 288 + col] : 0.0f;
    } else {                            // phi: rows 0-3 loc, 4-7 scale, k [h|fx]
        int ks = e - PB, col = ks * 32 + kl;
        if (row < 4) v = Wp_loc[row * 320 + col];
        else if (row < 8) v = Wp_scale[(row - 4) * 320 + col];
    }
    wfrag[idx] = f2h(v);
}

// fx = relu(x @ Wx^T + bx) for all (b,l), stored f16-packed [B][L][64].
__global__ __launch_bounds__(256) void fx_pre(const float* __restrict__ x,
                                              const float* __restrict__ Wx,
                                              const float* __restrict__ bx,
                                              ushort_t* __restrict__ fxbuf) {
    __shared__ float w[FXN][FN + 1];
    __shared__ float bxs[FXN];
    int t = threadIdx.x;
    for (int i = t; i < FXN * FN; i += 256) w[i / FN][i % FN] = Wx[i];
    if (t < FXN) bxs[t] = bx[t];
    __syncthreads();
    size_t id = (size_t)blockIdx.x * 256 + t;
    const float* xr = x + id * FN;
    float xv[FN];
#pragma unroll
    for (int f = 0; f < FN; ++f) xv[f] = xr[f];
    uint4* dst = (uint4*)(fxbuf + id * FXN);
#pragma unroll
    for (int e8 = 0; e8 < 8; ++e8) {
        float a[8];
#pragma unroll
        for (int u = 0; u < 8; ++u) {
            int e = e8 * 8 + u;
            float acc = bxs[e];
#pragma unroll
            for (int f = 0; f < FN; ++f) acc += xv[f] * w[e][f];
            a[u] = fmaxf(acc, 0.0f);
        }
        uint4 o;
        o.x = pk2(a[0], a[1]); o.y = pk2(a[2], a[3]);
        o.z = pk2(a[4], a[5]); o.w = pk2(a[6], a[7]);
        dst[e8] = o;
    }
}

// act-frag index: buffer buf, k-step ks -> base in ushorts (single n-tile)
#define AIDX(buf, ks) (((buf) * 11 + (ks)) * 512)

template <bool FXPRE>
__global__ __launch_bounds__(NT) void vrnn_mfma(
    const float* __restrict__ x, const float* __restrict__ eps,
    const float* __restrict__ Wx, const float* __restrict__ bx,
    const float* __restrict__ Wz1, const float* __restrict__ bz1,
    const float* __restrict__ Wz2, const float* __restrict__ bz2,
    const float* __restrict__ bp_loc, const float* __restrict__ bp_scale,
    const float* __restrict__ bt_loc,
    const float* __restrict__ b_ih, const float* __restrict__ b_hh,
    const ushort_t* __restrict__ wfrag, const ushort_t* __restrict__ fxbuf,
    float* __restrict__ out)
{
    __shared__ __attribute__((aligned(16))) ushort_t actf[2 * 11 * 512];     // 22.5 KB frags
    __shared__ __attribute__((aligned(16))) uint_t phif[10 * 64 * 4];        // phi A-frags
    __shared__ __attribute__((aligned(16))) ushort_t wext[75 * 512];         // in(48)+theta(27)
    __shared__ float pp[8][16];
    __shared__ float bsr[HN], bsz[HN], bin_[HN], bhn_[HN];
    __shared__ float wz1s[16][ZDN], wz2s[FZN][16];
    __shared__ float bz1s[16], bz2s[FZN], btls[FN], bpls[ZDN], bpss[ZDN];
    __shared__ float wxs[FXN][FN + 2], bxs[FXN];     // tier-B fx weights

    const int t = threadIdx.x;
    const int w = t >> 6, ln = t & 63;
    const int b0 = blockIdx.x * BT;
    const uint4* WL = ((const uint4*)wfrag) + ln;    // lane-offset entry table

    // ---- one-time init
    {
        const uint_t* wfu = (const uint_t*)wfrag;
        for (int i = t; i < 10 * 256; i += NT) phif[i] = wfu[PB * 256 + i];
        uint2* we2 = (uint2*)wext;
        const uint2* ws2 = ((const uint2*)wfrag) + IB * 128;
        for (int i = t; i < 75 * 128; i += NT) we2[i] = ws2[i];
    }
    if (t < HN) {
        bsr[t] = b_ih[t] + b_hh[t];
        bsz[t] = b_ih[HN + t] + b_hh[HN + t];
        bin_[t] = b_ih[2 * HN + t];
        bhn_[t] = b_hh[2 * HN + t];
    }
    if (t >= 256 && t < 320) ((float*)wz1s)[t - 256] = Wz1[t - 256];
    for (int i = t; i < FZN * 16; i += NT) ((float*)wz2s)[i] = Wz2[i];
    if (t < 16) bz1s[t] = bz1[t];
    if (t >= 32 && t < 64) bz2s[t - 32] = bz2[t - 32];
    if (t >= 64 && t < 64 + FN) btls[t - 64] = bt_loc[t - 64];
    if (t >= 128 && t < 132) bpls[t - 128] = bp_loc[t - 128];
    if (t >= 160 && t < 164) bpss[t - 160] = bp_scale[t - 160];
    if (!FXPRE) {
        for (int i = t; i < FXN * FN; i += NT) wxs[i / FN][i % FN] = Wx[i];
        if (t >= 320 && t < 384) bxs[t - 320] = bx[t - 320];
    }
    // zero h-region of buffer 0 (ksteps 0..7)
    for (int i = t; i < 8 * 512; i += NT) actf[AIDX(0, i >> 9) + (i & 511)] = 0;
    __syncthreads();
    // fx(l=0) into buffer 0 (threads 0..127: b 0..15, ch 0..7)
    if (t < 128) {
        int b = t >> 3, ch = t & 7;
        int dst = AIDX(0, 8 + (ch >> 2)) + ((ch & 3) * 16 + b) * 8;
        if (FXPRE) {
            uint4 v = ((const uint4*)fxbuf)[((size_t)(b0 + b) * LN) * 8 + ch];
            *(uint4*)&actf[dst] = v;
        } else {
            const float* xr = x + ((size_t)(b0 + b) * LN) * FN;
            uint_t o[4];
#pragma unroll
            for (int p = 0; p < 4; ++p) {
                float a0 = bxs[ch * 8 + 2 * p], a1 = bxs[ch * 8 + 2 * p + 1];
#pragma unroll
                for (int f = 0; f < FN; ++f) {
                    float xv = xr[f];
                    a0 += xv * wxs[ch * 8 + 2 * p][f];
                    a1 += xv * wxs[ch * 8 + 2 * p + 1][f];
                }
                o[p] = pk2(fmaxf(a0, 0.0f), fmaxf(a1, 0.0f));
            }
            *(uint4*)&actf[dst] = make_uint4(o[0], o[1], o[2], o[3]);
        }
    }
    __syncthreads();

    const int mtA = 2 * w, mtB = 2 * w + 1;

#pragma unroll 1
    for (int l = 0; l < LN; ++l) {
        const int cur = l & 1, nxt = cur ^ 1;

        // eps prefetch for CDE threads (waves 4-5)
        float4 pfe = {0, 0, 0, 0};
        if (t >= 256 && t < 384)
            pfe = *(const float4*)&eps[((size_t)l * BN + b0 + ((t - 256) >> 3)) * ZDN];

        // ---- fused MFMA loop, depth-2 rotation on r/z/hn A-frags
        f4 ra0 = {0,0,0,0}, rb0 = {0,0,0,0}, za0 = {0,0,0,0}, zb0 = {0,0,0,0};
        f4 na0 = {0,0,0,0}, nb0 = {0,0,0,0}, ia0 = {0,0,0,0}, ib0 = {0,0,0,0};
        f4 tp = {0,0,0,0};

        uint4 rac = WL[(RB + mtA * 11 + 0) * 64], rbc = WL[(RB + mtB * 11 + 0) * 64];
        uint4 zac = WL[(ZB + mtA * 11 + 0) * 64], zbc = WL[(ZB + mtB * 11 + 0) * 64];
        uint4 ran = WL[(RB + mtA * 11 + 1) * 64], rbn = WL[(RB + mtB * 11 + 1) * 64];
        uint4 zan = WL[(ZB + mtA * 11 + 1) * 64], zbn = WL[(ZB + mtB * 11 + 1) * 64];
        uint4 hac = WL[(HB + mtA * 8 + 0) * 64],  hbc = WL[(HB + mtB * 8 + 0) * 64];
        uint4 han = WL[(HB + mtA * 8 + 1) * 64],  hbn = WL[(HB + mtB * 8 + 1) * 64];

#pragma unroll
        for (int ks = 0; ks < 10; ++ks) {
            h8 B = *(const h8*)&actf[AIDX(cur, ks) + ln * 8];
            ra0 = MFMA(bch8(rac), B, ra0);
            rac = ran; if (ks < 9) ran = WL[(RB + mtA * 11 + ks + 2) * 64];
            rb0 = MFMA(bch8(rbc), B, rb0);
            rbc = rbn; if (ks < 9) rbn = WL[(RB + mtB * 11 + ks + 2) * 64];
            za0 = MFMA(bch8(zac), B, za0);
            zac = zan; if (ks < 9) zan = WL[(ZB + mtA * 11 + ks + 2) * 64];
            zb0 = MFMA(bch8(zbc), B, zb0);
            zbc = zbn; if (ks < 9) zbn = WL[(ZB + mtB * 11 + ks + 2) * 64];
            if (ks < 8) {
                na0 = MFMA(bch8(hac), B, na0);
                hac = han; if (ks < 6) han = WL[(HB + mtA * 8 + ks + 2) * 64];
                nb0 = MFMA(bch8(hbc), B, nb0);
                hbc = hbn; if (ks < 6) hbn = WL[(HB + mtB * 8 + ks + 2) * 64];
            } else {
                h8 wA = *(const h8*)&wext[(mtA * 3 + (ks - 8)) * 512 + ln * 8];
                h8 wB = *(const h8*)&wext[(mtB * 3 + (ks - 8)) * 512 + ln * 8];
                ia0 = MFMA(wA, B, ia0);
                ib0 = MFMA(wB, B, ib0);
            }
            if (w < 3) {
                if (ks < 8) {
                    h8 wt = *(const h8*)&wext[(48 + w * 9 + ks + 1) * 512 + ln * 8];
                    tp = MFMA(wt, B, tp);
                }
            } else if (w == 3) {
                uint4 pa = *(const uint4*)&phif[(ks * 64 + ln) * 4];
                tp = MFMA(bch8(pa), B, tp);
            }
        }
        if (w == 3 && (ln >> 4) < 2) {            // dump phi D -> pp
#pragma unroll
            for (int q = 0; q < 4; ++q) pp[(ln >> 4) * 4 + q][ln & 15] = tp[q];
        }
        __syncthreads();   // sync1: pp ready

        // ---- CDE (waves 4-5): z -> f1 -> fz; fx(l+1) staging (waves 6-7)
        if (t >= 256 && t < 384) {
            int tid = t - 256, b = tid >> 3, part = tid & 7;
            float ez[4] = {pfe.x, pfe.y, pfe.z, pfe.w};
            float zz[4];
#pragma unroll
            for (int c = 0; c < 4; ++c)
                zz[c] = pp[c][b] + bpls[c] + fsoftplus(pp[4 + c][b] + bpss[c]) * ez[c];
            float f1v[16];
#pragma unroll
            for (int k = 0; k < 16; ++k) {
                float a = bz1s[k];
#pragma unroll
                for (int c = 0; c < 4; ++c) a += zz[c] * wz1s[k][c];
                f1v[k] = fmaxf(a, 0.0f);
            }
            float v4[4];
#pragma unroll
            for (int oq = 0; oq < 4; ++oq) {
                int o = part * 4 + oq;
                float acc = bz2s[o];
#pragma unroll
                for (int k = 0; k < 16; ++k) acc += f1v[k] * wz2s[o][k];
                v4[oq] = fmaxf(acc, 0.0f);
            }
            uint2 pk; pk.x = pk2(v4[0], v4[1]); pk.y = pk2(v4[2], v4[3]);
            int dst = AIDX(cur, 10) + ((part >> 1) * 16 + b) * 8 + (part & 1) * 4;
            *(uint2*)&actf[dst] = pk;
        } else if (t >= 384) {
            int tid = t - 384, b = tid >> 3, ch = tid & 7;
            int lp = (l + 1 < LN) ? l + 1 : LN - 1;
            int dst = AIDX(nxt, 8 + (ch >> 2)) + ((ch & 3) * 16 + b) * 8;
            if (FXPRE) {
                uint4 v = ((const uint4*)fxbuf)[((size_t)(b0 + b) * LN + lp) * 8 + ch];
                *(uint4*)&actf[dst] = v;
            } else {
                const float* xr = x + ((size_t)(b0 + b) * LN + lp) * FN;
                uint_t o[4];
#pragma unroll
                for (int p = 0; p < 4; ++p) {
                    float a0 = bxs[ch * 8 + 2 * p], a1 = bxs[ch * 8 + 2 * p + 1];
#pragma unroll
                    for (int f = 0; f < FN; ++f) {
                        float xv = xr[f];
                        a0 += xv * wxs[ch * 8 + 2 * p][f];
                        a1 += xv * wxs[ch * 8 + 2 * p + 1][f];
                    }
                    o[p] = pk2(fmaxf(a0, 0.0f), fmaxf(a1, 0.0f));
                }
                *(uint4*)&actf[dst] = make_uint4(o[0], o[1], o[2], o[3]);
            }
        }
        __syncthreads();   // sync2: fz ready

        // ---- Phase B: fz kstep (rotated r/z regs hold ks10; in/theta from LDS)
        {
            h8 B = *(const h8*)&actf[AIDX(cur, 10) + ln * 8];
            ra0 = MFMA(bch8(rac), B, ra0);
            rb0 = MFMA(bch8(rbc), B, rb0);
            za0 = MFMA(bch8(zac), B, za0);
            zb0 = MFMA(bch8(zbc), B, zb0);
            h8 wA = *(const h8*)&wext[(mtA * 3 + 2) * 512 + ln * 8];
            h8 wB = *(const h8*)&wext[(mtB * 3 + 2) * 512 + ln * 8];
            ia0 = MFMA(wA, B, ia0);
            ib0 = MFMA(wB, B, ib0);
            if (w < 3) {
                h8 wt = *(const h8*)&wext[(48 + w * 9 + 0) * 512 + ln * 8];
                tp = MFMA(wt, B, tp);
            }
        }

#define PW(RACC, ZACC, NACC, IACC, MTL) do {                                        \
        int jb = (2 * w + (MTL)) * 16 + ((ln >> 4) << 2);                           \
        int abase = (((jb >> 3) & 3) * 16 + (ln & 15)) * 8 + (jb & 7);              \
        uint2 ho2 = *(const uint2*)&actf[AIDX(cur, jb >> 5) + abase];               \
        float ho[4] = { h2f((ushort_t)ho2.x), h2f((ushort_t)(ho2.x >> 16)),         \
                        h2f((ushort_t)ho2.y), h2f((ushort_t)(ho2.y >> 16)) };       \
        float hn4[4];                                                               \
        _Pragma("unroll")                                                           \
        for (int q = 0; q < 4; ++q) {                                               \
            float r_ = fsig((RACC)[q] + bsr[jb + q]);                               \
            float z_ = fsig((ZACC)[q] + bsz[jb + q]);                               \
            float n_ = ftanh((IACC)[q] + bin_[jb + q] + r_ * ((NACC)[q] + bhn_[jb + q])); \
            hn4[q] = (1.0f - z_) * n_ + z_ * ho[q];                                 \
        }                                                                           \
        uint2 hw2; hw2.x = pk2(hn4[0], hn4[1]); hw2.y = pk2(hn4[2], hn4[3]);        \
        *(uint2*)&actf[AIDX(nxt, jb >> 5) + abase] = hw2;                           \
    } while (0)

        PW(ra0, za0, na0, ia0, 0);
        PW(rb0, zb0, nb0, ib0, 1);
#undef PW

        if (w < 3) {    // theta store (mt w: f = w*16 + row)
            int bb = b0 + (ln & 15);
            float* op = out + ((size_t)bb * LN + l) * FN;
#pragma unroll
            for (int q = 0; q < 4; ++q) {
                int f = w * 16 + ((ln >> 4) << 2) + q;
                if (f < FN) op[f] = tp[q] + btls[f];
            }
        }
        __syncthreads();   // sync3
    }
}

extern "C" void kernel_launch(void* const* d_in, const int* in_sizes, int n_in,
                              void* d_out, int out_size, void* d_ws, size_t ws_size,
                              hipStream_t stream) {
    const float* x        = (const float*)d_in[0];
    const float* eps      = (const float*)d_in[1];
    const float* Wx       = (const float*)d_in[2];
    const float* bx       = (const float*)d_in[3];
    const float* Wz1      = (const float*)d_in[4];
    const float* bz1      = (const float*)d_in[5];
    const float* Wz2      = (const float*)d_in[6];
    const float* bz2      = (const float*)d_in[7];
    const float* Wp_loc   = (const float*)d_in[8];
    const float* bp_loc   = (const float*)d_in[9];
    const float* Wp_scale = (const float*)d_in[10];
    const float* bp_scale = (const float*)d_in[11];
    const float* Wt_loc   = (const float*)d_in[12];
    const float* bt_loc   = (const float*)d_in[13];
    const float* W_ih     = (const float*)d_in[16];
    const float* W_hh     = (const float*)d_in[17];
    const float* b_ih     = (const float*)d_in[18];
    const float* b_hh     = (const float*)d_in[19];
    float* out = (float*)d_out;

    const size_t wfS = (size_t)NENT * 512;        // shorts
    const size_t fxS = (size_t)BN * LN * FXN;     // shorts

    ushort_t* wfrag = (ushort_t*)d_ws;
    ushort_t* fxbuf = wfrag + wfS;

    repack_frags<<<(int)((wfS + 255) / 256), 256, 0, stream>>>(
        W_ih, W_hh, Wt_loc, Wp_loc, Wp_scale, wfrag);

    if (ws_size >= (wfS + fxS) * sizeof(ushort_t)) {
        fx_pre<<<BN * LN / 256, 256, 0, stream>>>(x, Wx, bx, fxbuf);
        vrnn_mfma<true><<<NWG, NT, 0, stream>>>(
            x, eps, Wx, bx, Wz1, bz1, Wz2, bz2, bp_loc, bp_scale, bt_loc,
            b_ih, b_hh, wfrag, fxbuf, out);
    } else {
        vrnn_mfma<false><<<NWG, NT, 0, stream>>>(
            x, eps, Wx, bx, Wz1, bz1, Wz2, bz2, bp_loc, bp_scale, bt_loc,
            b_ih, b_hh, wfrag, (const ushort_t*)nullptr, out);
    }
}